// Round 1
// baseline (288.564 us; speedup 1.0000x reference)
//
#include <hip/hip_runtime.h>
#include <math.h>

#define RBINS 160
#define BROWS 65536
#define ROWS_PER_BLOCK 8
#define NTHREADS 960                 // 2 rows * 480 elems, 15 full waves
#define NELEM (BROWS * RBINS * 3)    // 31,457,280

__device__ __forceinline__ float clamp01(float x) {
    return __builtin_amdgcn_fmed3f(x, 0.0f, 1.0f);
}

// out[b,j,c] = fade[j] * ( cc*work[j] + kk*work[j-1] + kk*work[j+1] )
// work[p]    = sum over sources i with left(i)==p of h1[i]*wl(i)
//            + sum over sources i with left(i)+1==p of h1[i]*wr(i)
// h1[i]      = clamp01( h0[i] + (i<5 ? color*amount*w[i] : 0) )
// Since left(i) = i + d (+1 in rare f32-rounding cases), out[j] only sees
// sources i in [j-d-3, j-d+2] -> 6-tap window; coefficients per (j,t) are
// data-independent -> precompute table g[j][t] in LDS per block.
__global__ __launch_bounds__(NTHREADS, 1) void beat_kernel(
    const float* __restrict__ hist,
    const float* __restrict__ color,
    const float* __restrict__ p_offset,
    const float* __restrict__ p_persist,
    const float* __restrict__ p_diff,
    const float* __restrict__ p_dt,
    const float* __restrict__ p_amount,
    const float* __restrict__ p_spread,
    float* __restrict__ out)
{
    __shared__ float g_lds[RBINS][8];   // 6 used, pad to 8 (32B rows)
    __shared__ float aw_lds[8];
    __shared__ int   d_lds;

    const int tid = threadIdx.x;

    // ---- per-block coefficient table build (threads 0..159) ----
    if (tid < RBINS) {
        const float offs = *p_offset;
        const float pers = *p_persist;
        const float diff = *p_diff;
        const float dts  = *p_dt;

        const float dt       = fminf(fmaxf(dts, 0.0f), 0.05f);
        const float dt_scale = dt * 60.0f;
        const float s        = offs * dt_scale;          // uniform shift
        const float dt_pers  = powf(pers, dt_scale);
        const int   dfl      = (int)floorf(s);
        const float kk = 0.15f * diff;
        const float cc = 1.0f - 2.0f * kk;

        const int j = tid;
        float fade = 1.0f;
        if (j >= RBINS - 8) {
            float tt = (float)(RBINS - 1 - j) * 0.125f;
            fade = tt * tt;
        }
        const int i0 = min(max(j - dfl - 3, -8), RBINS);

        #pragma unroll
        for (int t = 0; t < 6; ++t) {
            float coef = 0.0f;
            int i = i0 + t;
            if (i >= 0 && i < RBINS) {
                float np_ = (float)i + s;                 // f32, mirrors ref
                if (np_ >= 0.0f && np_ < (float)(RBINS - 1)) {
                    int left = (int)floorf(np_);
                    left = min(max(left, 0), RBINS - 2);
                    float frac = np_ - (float)left;
                    float wl = (1.0f - frac) * dt_pers;
                    float wr = frac * dt_pers;
                    int dl = j - left;                    // dest offset of wl tap
                    int dr = j - (left + 1);              // dest offset of wr tap
                    float cl = (dl == 0) ? cc : ((dl == 1 || dl == -1) ? kk : 0.0f);
                    float cr = (dr == 0) ? cc : ((dr == 1 || dr == -1) ? kk : 0.0f);
                    coef = wl * cl + wr * cr;
                }
            }
            g_lds[j][t] = coef * fade;
        }
        if (tid == 0) {
            const float am = fminf(fmaxf(*p_amount, 0.0f), 1.0f);
            const float sp = fminf(fmaxf(*p_spread, 0.0f), 1.0f);
            const float tight = 1.0f - sp;
            aw_lds[0] = am * (0.5f + 0.4f * tight);
            aw_lds[1] = am * (0.2f * sp + 0.05f);
            aw_lds[2] = am * (0.12f * sp);
            aw_lds[3] = am * (0.06f * sp);
            aw_lds[4] = am * (0.02f * sp);
            d_lds = dfl;
        }
    }
    __syncthreads();

    // ---- streaming phase: thread owns (j,c) of two row-slots, 4 row-pairs ----
    const int rowoff = (tid >= 480) ? 1 : 0;
    const int rr = tid - 480 * rowoff;       // element within row [0,480)
    const int j  = rr / 3;
    const int c  = rr - 3 * j;
    const int dfl = d_lds;
    const int i0 = min(max(j - dfl - 3, -8), RBINS);
    const int b0 = blockIdx.x * ROWS_PER_BLOCK + rowoff;

    const float g0 = g_lds[j][0], g1 = g_lds[j][1], g2 = g_lds[j][2];
    const float g3 = g_lds[j][3], g4 = g_lds[j][4], g5 = g_lds[j][5];

    const bool fast = (i0 >= 5) && (i0 + 5 < RBINS);
    if (fast) {
        // taps never touch injected bins and never leave the row
        #pragma unroll
        for (int k = 0; k < ROWS_PER_BLOCK / 2; ++k) {
            int b = b0 + 2 * k;
            const float* p = hist + (b * 480 + i0 * 3 + c);
            float acc;
            acc  = g0 * clamp01(p[0]);
            acc += g1 * clamp01(p[3]);
            acc += g2 * clamp01(p[6]);
            acc += g3 * clamp01(p[9]);
            acc += g4 * clamp01(p[12]);
            acc += g5 * clamp01(p[15]);
            out[b * 480 + rr] = acc;
        }
    } else {
        // inject window and/or row boundary: per-tap safe addressing
        #pragma unroll
        for (int k = 0; k < ROWS_PER_BLOCK / 2; ++k) {
            int b = b0 + 2 * k;
            float colv = color[b * 3 + c];
            float acc = 0.0f;
            #pragma unroll
            for (int t = 0; t < 6; ++t) {
                int i = i0 + t;
                unsigned fl = (unsigned)(b * 480 + i * 3 + c);
                fl = min(fl, (unsigned)(NELEM - 1));     // neg wraps -> clamped
                float v = hist[fl];
                if ((unsigned)i < 5u) v = v + colv * aw_lds[i];
                v = clamp01(v);
                float gg = (t == 0) ? g0 : (t == 1) ? g1 : (t == 2) ? g2
                         : (t == 3) ? g3 : (t == 4) ? g4 : g5;
                acc += gg * v;   // gg==0 whenever i outside [0,R)
            }
            out[b * 480 + rr] = acc;
        }
    }
}

extern "C" void kernel_launch(void* const* d_in, const int* in_sizes, int n_in,
                              void* d_out, int out_size, void* d_ws, size_t ws_size,
                              hipStream_t stream) {
    const float* hist      = (const float*)d_in[0];
    const float* color     = (const float*)d_in[1];
    const float* p_offset  = (const float*)d_in[2];
    const float* p_persist = (const float*)d_in[3];
    const float* p_diff    = (const float*)d_in[4];
    const float* p_dt      = (const float*)d_in[5];
    const float* p_amount  = (const float*)d_in[6];
    const float* p_spread  = (const float*)d_in[7];
    float* outp = (float*)d_out;

    dim3 grid(BROWS / ROWS_PER_BLOCK);   // 8192 blocks
    dim3 block(NTHREADS);                // 960 threads = 15 waves
    beat_kernel<<<grid, block, 0, stream>>>(hist, color, p_offset, p_persist,
                                            p_diff, p_dt, p_amount, p_spread,
                                            outp);
}

// Round 2
// 247.871 us; speedup vs baseline: 1.1642x; 1.1642x over previous
//
#include <hip/hip_runtime.h>
#include <math.h>

#define RBINS 160
#define BROWS 65536
#define ROWELEMS 480                  // 160 bins * 3 channels
#define NELEM (BROWS * ROWELEMS)      // 31,457,280
#define COLS 40                       // 40 threads * 12 floats = one row
#define ITER 4                        // rows per thread
#define NSLOTS (BROWS / ITER)         // 16384 row-slots
#define NTHREADS 256
#define NBLOCKS (NSLOTS * COLS / NTHREADS)  // 2560 blocks

__device__ __forceinline__ float clamp01(float x) {
    return __builtin_amdgcn_fmed3f(x, 0.0f, 1.0f);
}

// Each thread: outputs [e0, e0+12) of a row = bins j0..j0+3, all 3 channels.
// out[e] = sum_t g[e/3][t] * x[e - S + 3t],  S = (dfl+3)*3, x = clamp01(h+inject).
// Window [a0, a0+32) with a0 = e0 - S - p, p = (-S)&3 (wave-uniform) -> 8 dwordx4.
// Taps with element index outside [0,480) have g==0 by table construction, so
// address-clamped garbage loads are multiplied by zero.
template<int P>
__device__ __forceinline__ void process_rows(
    const float* __restrict__ hist, const float* __restrict__ color,
    float* __restrict__ out, int slot, int a0, int e0,
    const float* gp /*LDS &g[j0*6]*/, const float* aw /*LDS*/, bool need_inject)
{
    float G[24];
    #pragma unroll
    for (int q = 0; q < 24; ++q) G[q] = gp[q];

    const float4* src = (const float4*)hist;
    for (int it = 0; it < ITER; ++it) {
        const int b = it * NSLOTS + slot;
        const int base = b * ROWELEMS;
        float w[32];
        const int f0 = (base + a0) >> 2;       // base+a0 is a multiple of 4
        #pragma unroll
        for (int q = 0; q < 8; ++q) {
            int f = f0 + q;
            f = min(max(f, 0), NELEM / 4 - 1); // clamp: OOB taps have g==0
            float4 v = src[f];
            w[4*q+0] = v.x; w[4*q+1] = v.y; w[4*q+2] = v.z; w[4*q+3] = v.w;
        }
        if (need_inject) {                     // rare: window touches bins i<5
            const float c0 = color[b*3+0], c1 = color[b*3+1], c2 = color[b*3+2];
            #pragma unroll
            for (int u = 0; u < 32; ++u) {
                const int e = a0 + u;
                if (e >= 0 && e < 15) {
                    const int i  = e / 3;
                    const int cc = e - 3*i;
                    const float cv = (cc == 0) ? c0 : ((cc == 1) ? c1 : c2);
                    w[u] += cv * aw[i];
                }
            }
        }
        #pragma unroll
        for (int u = 0; u < 32; ++u) w[u] = clamp01(w[u]);

        float r[12];
        #pragma unroll
        for (int m = 0; m < 12; ++m) {
            const int gb = (m / 3) * 6;
            float acc = G[gb+0] * w[P+m];
            acc += G[gb+1] * w[P+m+3];
            acc += G[gb+2] * w[P+m+6];
            acc += G[gb+3] * w[P+m+9];
            acc += G[gb+4] * w[P+m+12];
            acc += G[gb+5] * w[P+m+15];
            r[m] = acc;
        }
        float4* dst = (float4*)(out + base + e0);
        dst[0] = make_float4(r[0], r[1], r[2],  r[3]);
        dst[1] = make_float4(r[4], r[5], r[6],  r[7]);
        dst[2] = make_float4(r[8], r[9], r[10], r[11]);
    }
}

__global__ __launch_bounds__(NTHREADS, 4) void beat_kernel(
    const float* __restrict__ hist,
    const float* __restrict__ color,
    const float* __restrict__ p_offset,
    const float* __restrict__ p_persist,
    const float* __restrict__ p_diff,
    const float* __restrict__ p_dt,
    const float* __restrict__ p_amount,
    const float* __restrict__ p_spread,
    float* __restrict__ out)
{
    __shared__ float g_lds[RBINS * 6];
    __shared__ float aw_lds[8];
    __shared__ int   d_lds;

    const int tid = threadIdx.x;

    // ---- per-block coefficient table (threads 0..159), mirrors ref f32 math ----
    if (tid < RBINS) {
        const float offs = *p_offset;
        const float pers = *p_persist;
        const float diff = *p_diff;
        const float dts  = *p_dt;

        const float dt       = fminf(fmaxf(dts, 0.0f), 0.05f);
        const float dt_scale = dt * 60.0f;
        const float s        = offs * dt_scale;
        const float dt_pers  = powf(pers, dt_scale);
        const int   dfl      = (int)floorf(s);
        const float kk = 0.15f * diff;
        const float cc = 1.0f - 2.0f * kk;

        const int j = tid;
        float fade = 1.0f;
        if (j >= RBINS - 8) {
            const float tt = (float)(RBINS - 1 - j) * 0.125f;
            fade = tt * tt;
        }
        const int i0 = j - dfl - 3;
        #pragma unroll
        for (int t = 0; t < 6; ++t) {
            float coef = 0.0f;
            const int i = i0 + t;
            if (i >= 0 && i < RBINS) {
                const float np_ = (float)i + s;            // f32, mirrors ref
                if (np_ >= 0.0f && np_ < (float)(RBINS - 1)) {
                    int left = (int)floorf(np_);
                    left = min(max(left, 0), RBINS - 2);
                    const float frac = np_ - (float)left;
                    const float wl = (1.0f - frac) * dt_pers;
                    const float wr = frac * dt_pers;
                    const int dl = j - left;
                    const int dr = j - (left + 1);
                    const float cl = (dl == 0) ? cc : ((dl == 1 || dl == -1) ? kk : 0.0f);
                    const float cr = (dr == 0) ? cc : ((dr == 1 || dr == -1) ? kk : 0.0f);
                    coef = wl * cl + wr * cr;
                }
            }
            g_lds[j * 6 + t] = coef * fade;
        }
        if (tid == 0) {
            const float am = fminf(fmaxf(*p_amount, 0.0f), 1.0f);
            const float sp = fminf(fmaxf(*p_spread, 0.0f), 1.0f);
            const float tight = 1.0f - sp;
            aw_lds[0] = am * (0.5f + 0.4f * tight);
            aw_lds[1] = am * (0.2f * sp + 0.05f);
            aw_lds[2] = am * (0.12f * sp);
            aw_lds[3] = am * (0.06f * sp);
            aw_lds[4] = am * (0.02f * sp);
            d_lds = dfl;
        }
    }
    __syncthreads();

    const int gid  = blockIdx.x * NTHREADS + tid;
    const int col  = gid % COLS;
    const int slot = gid / COLS;
    const int e0   = col * 12;
    const int j0   = col * 4;

    const int dfl = d_lds;
    const int S   = (dfl + 3) * 3;
    const int p   = (-S) & 3;
    const int a0  = e0 - S - p;
    const bool need_inject = (a0 < 15) && (a0 + 31 >= 0);

    const float* gp = &g_lds[j0 * 6];
    switch (p) {
        case 0: process_rows<0>(hist, color, out, slot, a0, e0, gp, aw_lds, need_inject); break;
        case 1: process_rows<1>(hist, color, out, slot, a0, e0, gp, aw_lds, need_inject); break;
        case 2: process_rows<2>(hist, color, out, slot, a0, e0, gp, aw_lds, need_inject); break;
        default: process_rows<3>(hist, color, out, slot, a0, e0, gp, aw_lds, need_inject); break;
    }
}

extern "C" void kernel_launch(void* const* d_in, const int* in_sizes, int n_in,
                              void* d_out, int out_size, void* d_ws, size_t ws_size,
                              hipStream_t stream) {
    const float* hist      = (const float*)d_in[0];
    const float* color     = (const float*)d_in[1];
    const float* p_offset  = (const float*)d_in[2];
    const float* p_persist = (const float*)d_in[3];
    const float* p_diff    = (const float*)d_in[4];
    const float* p_dt      = (const float*)d_in[5];
    const float* p_amount  = (const float*)d_in[6];
    const float* p_spread  = (const float*)d_in[7];
    float* outp = (float*)d_out;

    beat_kernel<<<dim3(NBLOCKS), dim3(NTHREADS), 0, stream>>>(
        hist, color, p_offset, p_persist, p_diff, p_dt, p_amount, p_spread, outp);
}

// Round 4
// 236.667 us; speedup vs baseline: 1.2193x; 1.0473x over previous
//
#include <hip/hip_runtime.h>
#include <math.h>

#define RBINS 160
#define BROWS 65536
#define ROWELEMS 480                    // 160 bins * 3 channels
#define NELEM (BROWS * ROWELEMS)        // 31,457,280
#define TILE_ROWS 8
#define TILE_F (TILE_ROWS * ROWELEMS)   // 3840 floats staged per block
#define TILE_F4 (TILE_F / 4)            // 960 float4
#define NTHREADS 320                    // 5 waves; 320 = 8 rows * 40 col-tasks
#define NBLOCKS (BROWS / TILE_ROWS)     // 8192

__device__ __forceinline__ float clamp01(float x) {
    return __builtin_amdgcn_fmed3f(x, 0.0f, 1.0f);
}

// Compute 12 outputs (4 bins x 3ch) from a 32-float LDS window.
// Taps with element index outside the source row have g==0 by table
// construction, so index-clamped garbage is multiplied by zero.
template<int P>
__device__ __forceinline__ void compute_store(
    const float4* __restrict__ tile4, const float* __restrict__ gp,
    float* __restrict__ outp, int w4base)
{
    float w[32];
    #pragma unroll
    for (int q = 0; q < 8; ++q) {
        int idx = w4base + q;
        idx = min(max(idx, 0), TILE_F4 - 1);   // clamp: OOB taps have g==0
        float4 v = tile4[idx];
        w[4*q+0] = v.x; w[4*q+1] = v.y; w[4*q+2] = v.z; w[4*q+3] = v.w;
    }
    #pragma unroll
    for (int u = 0; u < 32; ++u) w[u] = clamp01(w[u]);

    float G[24];
    #pragma unroll
    for (int q = 0; q < 24; ++q) G[q] = gp[q];

    float r[12];
    #pragma unroll
    for (int m = 0; m < 12; ++m) {
        const int gb = (m / 3) * 6;
        float acc = G[gb+0] * w[P+m+0];
        acc += G[gb+1] * w[P+m+3];
        acc += G[gb+2] * w[P+m+6];
        acc += G[gb+3] * w[P+m+9];
        acc += G[gb+4] * w[P+m+12];
        acc += G[gb+5] * w[P+m+15];
        r[m] = acc;
    }
    float4* dst = (float4*)outp;
    dst[0] = make_float4(r[0], r[1], r[2],  r[3]);
    dst[1] = make_float4(r[4], r[5], r[6],  r[7]);
    dst[2] = make_float4(r[8], r[9], r[10], r[11]);
}

__global__ __launch_bounds__(NTHREADS, 4) void beat_kernel(
    const float* __restrict__ hist,
    const float* __restrict__ color,
    const float* __restrict__ p_offset,
    const float* __restrict__ p_persist,
    const float* __restrict__ p_diff,
    const float* __restrict__ p_dt,
    const float* __restrict__ p_amount,
    const float* __restrict__ p_spread,
    float* __restrict__ out)
{
    __shared__ float tile[TILE_F];      // 15360 B staged input rows
    __shared__ float g_lds[RBINS * 6];  // 3840 B coefficient table
    __shared__ float aw_lds[8];
    __shared__ int   d_lds;

    const int tid = threadIdx.x;

    // ---- phase 1: coefficient table (threads 0..159), mirrors ref f32 math ----
    if (tid < RBINS) {
        const float offs = *p_offset;
        const float pers = *p_persist;
        const float diff = *p_diff;
        const float dts  = *p_dt;

        const float dt       = fminf(fmaxf(dts, 0.0f), 0.05f);
        const float dt_scale = dt * 60.0f;
        const float s        = offs * dt_scale;
        const float dt_pers  = powf(pers, dt_scale);
        const int   dfl      = (int)floorf(s);
        const float kk = 0.15f * diff;
        const float cc = 1.0f - 2.0f * kk;

        const int j = tid;
        float fade = 1.0f;
        if (j >= RBINS - 8) {
            const float tt = (float)(RBINS - 1 - j) * 0.125f;
            fade = tt * tt;
        }
        const int i0 = j - dfl - 3;
        #pragma unroll
        for (int t = 0; t < 6; ++t) {
            float coef = 0.0f;
            const int i = i0 + t;
            if (i >= 0 && i < RBINS) {
                const float np_ = (float)i + s;            // f32, mirrors ref
                if (np_ >= 0.0f && np_ < (float)(RBINS - 1)) {
                    int left = (int)floorf(np_);
                    left = min(max(left, 0), RBINS - 2);
                    const float frac = np_ - (float)left;
                    const float wl = (1.0f - frac) * dt_pers;
                    const float wr = frac * dt_pers;
                    const int dl = j - left;
                    const int dr = j - (left + 1);
                    const float cl = (dl == 0) ? cc : ((dl == 1 || dl == -1) ? kk : 0.0f);
                    const float cr = (dr == 0) ? cc : ((dr == 1 || dr == -1) ? kk : 0.0f);
                    coef = wl * cl + wr * cr;
                }
            }
            g_lds[j * 6 + t] = coef * fade;
        }
        if (tid == 0) {
            const float am = fminf(fmaxf(*p_amount, 0.0f), 1.0f);
            const float sp = fminf(fmaxf(*p_spread, 0.0f), 1.0f);
            const float tight = 1.0f - sp;
            aw_lds[0] = am * (0.5f + 0.4f * tight);
            aw_lds[1] = am * (0.2f * sp + 0.05f);
            aw_lds[2] = am * (0.12f * sp);
            aw_lds[3] = am * (0.06f * sp);
            aw_lds[4] = am * (0.02f * sp);
            d_lds = dfl;
        }
    }

    // ---- phase 2: stage 8 rows, fully coalesced (lane-contiguous float4) ----
    {
        const float4* src = (const float4*)hist;
        float4* t4 = (float4*)tile;
        const int base4 = blockIdx.x * TILE_F4;
        #pragma unroll
        for (int q = 0; q < TILE_F4 / NTHREADS; ++q) {   // 3 iters
            const int idx = q * NTHREADS + tid;
            t4[idx] = src[base4 + idx];
        }
    }
    __syncthreads();

    // ---- phase 3: injection into first 5 bins of each staged row ----
    if (tid < TILE_ROWS * 15) {
        const int r = tid / 15;
        const int e = tid - r * 15;
        const int i = e / 3;
        const int ch = e - 3 * i;
        const int b = blockIdx.x * TILE_ROWS + r;
        tile[r * ROWELEMS + e] += color[b * 3 + ch] * aw_lds[i];
    }
    __syncthreads();

    // ---- phase 4: windowed 6-tap compute from LDS ----
    const int r  = tid / 40;
    const int c  = tid - r * 40;
    const int e0 = c * 12;
    const int j0 = c * 4;

    const int dfl = d_lds;
    const int S   = (dfl + 3) * 3;
    const int p   = (-S) & 3;           // makes a0 a multiple of 4
    const int a0  = e0 - S - p;
    const int w4base = r * (ROWELEMS / 4) + (a0 >> 2);

    const float* gp = &g_lds[j0 * 6];
    float* outp = out + (blockIdx.x * TILE_ROWS + r) * ROWELEMS + e0;
    const float4* tile4 = (const float4*)tile;

    switch (p) {
        case 0:  compute_store<0>(tile4, gp, outp, w4base); break;
        case 1:  compute_store<1>(tile4, gp, outp, w4base); break;
        case 2:  compute_store<2>(tile4, gp, outp, w4base); break;
        default: compute_store<3>(tile4, gp, outp, w4base); break;
    }
}

extern "C" void kernel_launch(void* const* d_in, const int* in_sizes, int n_in,
                              void* d_out, int out_size, void* d_ws, size_t ws_size,
                              hipStream_t stream) {
    const float* hist      = (const float*)d_in[0];
    const float* color     = (const float*)d_in[1];
    const float* p_offset  = (const float*)d_in[2];
    const float* p_persist = (const float*)d_in[3];
    const float* p_diff    = (const float*)d_in[4];
    const float* p_dt      = (const float*)d_in[5];
    const float* p_amount  = (const float*)d_in[6];
    const float* p_spread  = (const float*)d_in[7];
    float* outp = (float*)d_out;

    beat_kernel<<<dim3(NBLOCKS), dim3(NTHREADS), 0, stream>>>(
        hist, color, p_offset, p_persist, p_diff, p_dt, p_amount, p_spread, outp);
}